// Round 7
// baseline (333.782 us; speedup 1.0000x reference)
//
#include <hip/hip_runtime.h>

namespace {

constexpr int B  = 16;
constexpr int D  = 128;
constexpr int C  = 6;
constexpr int H  = 128;
constexpr int W  = 128;
constexpr int HWC = H * W;          // 16384
constexpr int HO = 512, WO = 512;   // 4x upsample
constexpr int PXC = 1024;           // px per block in k_cls

// ---------------------------------------------------------------------------
// k_cls: px-ownership pass, DRAM-pattern-tuned.
// Evidence ladder (R2..R6): per-WAVE run length decides HBM BW:
//   256B->2.4, 1KB->2.8, >=32KB->5.8 TB/s. Fix: tile [8 d][1024 px] (32KB),
//   each wave stages 2 whole rows = 4KB sequential runs; barriers keep the
//   block's window tight (8 x 4KB). Two-deep A/B register prefetch (static
//   unroll; runtime-indexed reg arrays would spill) covers latency at
//   1 block/CU. Weights via LDS broadcast (not per-iter s_load - R2 lesson).
// Thread owns 4 px; 6 float4 dot accumulators; argmax; x/mask/counts.
// ---------------------------------------------------------------------------
__global__ __launch_bounds__(256) void k_cls(const float* __restrict__ assp,
                                             const float* __restrict__ cls_w,
                                             const float* __restrict__ cls_b,
                                             float* __restrict__ x,
                                             unsigned char* __restrict__ mask,
                                             int* __restrict__ counts) {
  __shared__ float tile[8 * PXC];     // 32 KB
  __shared__ float wlds[D * C];       // 3 KB, wlds[d*6+c]

  const int t    = threadIdx.x;
  const int b    = blockIdx.y;
  const int lane = t & 63;
  const int wv   = t >> 6;
  const int px0  = blockIdx.x * PXC;

  const float* base = assp + ((size_t)b * D) * HWC + px0;

  // issue tile 0 and tile 1 loads immediately (2-deep pipeline)
  float4 va[8], vb[8];
#pragma unroll
  for (int r = 0; r < 2; ++r)
#pragma unroll
    for (int i = 0; i < 4; ++i) {
      va[r * 4 + i] = *(const float4*)(base + (size_t)(0 * 8 + 2 * wv + r) * HWC + i * 256 + lane * 4);
      vb[r * 4 + i] = *(const float4*)(base + (size_t)(1 * 8 + 2 * wv + r) * HWC + i * 256 + lane * 4);
    }

  // transposed weights -> LDS (overlaps with in-flight tile loads)
  for (int i = t; i < D * C; i += 256) {
    int d = i / C, c = i - d * C;
    wlds[i] = cls_w[c * D + d];
  }

  float4 a[C];
#pragma unroll
  for (int c = 0; c < C; ++c) a[c] = {0.f, 0.f, 0.f, 0.f};

#define STORE_T(V)                                                         \
  _Pragma("unroll") for (int r = 0; r < 2; ++r)                            \
  _Pragma("unroll") for (int i = 0; i < 4; ++i)                            \
    *(float4*)&tile[(2 * wv + r) * PXC + i * 256 + lane * 4] = V[r * 4 + i];

#define LOAD_T(V, DS)                                                      \
  _Pragma("unroll") for (int r = 0; r < 2; ++r)                            \
  _Pragma("unroll") for (int i = 0; i < 4; ++i)                            \
    V[r * 4 + i] = *(const float4*)(base + (size_t)((DS) * 8 + 2 * wv + r) * HWC + i * 256 + lane * 4);

#define COMPUTE_T(DS)                                                      \
  _Pragma("unroll") for (int dd = 0; dd < 8; ++dd) {                       \
    float4 u = *(const float4*)&tile[dd * PXC + t * 4];                    \
    _Pragma("unroll") for (int c = 0; c < C; ++c) {                        \
      float wgt = wlds[((DS) * 8 + dd) * C + c];                           \
      a[c].x += u.x * wgt; a[c].y += u.y * wgt;                            \
      a[c].z += u.z * wgt; a[c].w += u.w * wgt;                            \
    }                                                                      \
  }

  for (int ds = 0; ds < 16; ds += 2) {
    STORE_T(va);
    __syncthreads();
    if (ds + 2 < 16) { LOAD_T(va, ds + 2); }
    COMPUTE_T(ds);
    __syncthreads();

    STORE_T(vb);
    __syncthreads();
    if (ds + 3 < 16) { LOAD_T(vb, ds + 3); }
    COMPUTE_T(ds + 1);
    __syncthreads();
  }
#undef STORE_T
#undef LOAD_T
#undef COMPUTE_T

  // ---- per-px argmax (first-wins == jnp.argmax) over 4 owned px ----
  int cls[4];
#pragma unroll
  for (int j = 0; j < 4; ++j) {
    float bv = (&a[0].x)[j] + cls_b[0];
    int bc = 0;
#pragma unroll
    for (int c = 1; c < C; ++c) {
      float pv = (&a[c].x)[j] + cls_b[c];
      if (pv > bv) { bv = pv; bc = c; }
    }
    cls[j] = bc;
  }

  // x = pseudo/12 + bias  (softmax(...,axis=1).mean(axis=1) == 1/12)
  const float inv12 = 1.0f / 12.0f;
  float* xb = x + ((size_t)b * C) * HWC + px0 + t * 4;
#pragma unroll
  for (int c = 0; c < C; ++c) {
    float4 o = {a[c].x * inv12 + cls_b[c], a[c].y * inv12 + cls_b[c],
                a[c].z * inv12 + cls_b[c], a[c].w * inv12 + cls_b[c]};
    *(float4*)(xb + (size_t)c * HWC) = o;
  }

  uchar4 m4 = {(unsigned char)cls[0], (unsigned char)cls[1],
               (unsigned char)cls[2], (unsigned char)cls[3]};
  *(uchar4*)(mask + (size_t)b * HWC + px0 + t * 4) = m4;

  // counts: 24 ballots, 6 atomics per wave
  int cnt = 0;
#pragma unroll
  for (int j = 0; j < 4; ++j)
#pragma unroll
    for (int c = 0; c < C; ++c) {
      unsigned long long m = __ballot(cls[j] == c);
      if (lane == c) cnt += (int)__popcll(m);
    }
  if (lane < C) atomicAdd(&counts[b * C + lane], cnt);
}

// ---------------------------------------------------------------------------
// k_sum: d-ownership streaming pass, proven ~5.8 TB/s (32KB sequential/wave).
// One wave per (b, d, 8192-px half row): float4 + uchar4 mask loads; 6
// register accumulators; butterfly reduce; 6 atomics/wave. No LDS/barriers.
// ---------------------------------------------------------------------------
__global__ __launch_bounds__(256) void k_sum(const float* __restrict__ assp,
                                             const unsigned char* __restrict__ mask,
                                             float* __restrict__ sums) {
  const int t    = threadIdx.x;
  const int lane = t & 63;
  const int wv   = t >> 6;
  const int b    = blockIdx.z;
  const int d    = blockIdx.y * 4 + wv;
  const int px0  = blockIdx.x * 8192;

  const float* row = assp + ((size_t)b * D + d) * HWC + px0;
  const unsigned char* mrow = mask + (size_t)b * HWC + px0;

  float acc[C] = {0.f, 0.f, 0.f, 0.f, 0.f, 0.f};
#pragma unroll 8
  for (int i = 0; i < 32; ++i) {
    float4 vv = *(const float4*)(row + i * 256 + lane * 4);
    uchar4 mm = *(const uchar4*)(mrow + i * 256 + lane * 4);
#pragma unroll
    for (int cc = 0; cc < C; ++cc) {
      acc[cc] += (mm.x == cc) ? vv.x : 0.f;
      acc[cc] += (mm.y == cc) ? vv.y : 0.f;
      acc[cc] += (mm.z == cc) ? vv.z : 0.f;
      acc[cc] += (mm.w == cc) ? vv.w : 0.f;
    }
  }

  float out = 0.f;
#pragma unroll
  for (int cc = 0; cc < C; ++cc) {
    float s = acc[cc];
#pragma unroll
    for (int off = 32; off >= 1; off >>= 1) s += __shfl_xor(s, off, 64);
    if (lane == cc) out = s;
  }
  if (lane < C) atomicAdd(&sums[((size_t)b * C + lane) * D + d], out);
}

// ---------------------------------------------------------------------------
// K3: per dropped pixel: protoC on the fly from sums/counts, nearest proto
// (first-wins argmin == over the 12=2x6 duplicated list), patch x directly.
// one wave per (b,p); lane owns d and d+64
// ---------------------------------------------------------------------------
__global__ void k_patch(const float* __restrict__ assp,
                        const float* __restrict__ sums,
                        const int* __restrict__ counts,
                        const float* __restrict__ cls_w,
                        const float* __restrict__ cls_b,
                        const int* __restrict__ px,
                        const int* __restrict__ py,
                        int P,
                        float* __restrict__ x) {
  int bp = blockIdx.x;
  int b = bp / P, p = bp % P;
  int hw = px[p] * W + py[p];
  int lane = threadIdx.x;                  // 64 threads = 1 wave
  const float* fbase = assp + ((size_t)b * D) * HWC + hw;

  float f0 = fbase[(size_t)lane * HWC];
  float f1 = fbase[(size_t)(lane + 64) * HWC];

  float pv0[C], pv1[C], ds[C];
#pragma unroll
  for (int c = 0; c < C; ++c) {
    float cnt = (float)counts[b * C + c];
    float s0 = sums[((size_t)b * C + c) * D + lane];
    float s1 = sums[((size_t)b * C + c) * D + lane + 64];
    float q0 = (cnt > 0.f) ? s0 / (cnt + 1e-5f) : 0.f;
    float q1 = (cnt > 0.f) ? s1 / (cnt + 1e-5f) : 0.f;
    pv0[c] = q0; pv1[c] = q1;
    float e0 = q0 - f0, e1 = q1 - f1;
    float tt = e0 * e0 + e1 * e1;
#pragma unroll
    for (int off = 32; off >= 1; off >>= 1) tt += __shfl_xor(tt, off, 64);
    ds[c] = tt;                            // identical on all lanes
  }
  int best = 0; float bv = ds[0];          // first-wins ties == jnp.argmin
#pragma unroll
  for (int c = 1; c < C; ++c)
    if (ds[c] < bv) { bv = ds[c]; best = c; }

  float v0 = 0.f, v1 = 0.f;                // select without dynamic indexing
#pragma unroll
  for (int c = 0; c < C; ++c) {
    if (best == c) { v0 = pv0[c]; v1 = pv1[c]; }
  }

  float myx = 0.f;
#pragma unroll
  for (int c = 0; c < C; ++c) {
    float tt = v0 * cls_w[c * D + lane] + v1 * cls_w[c * D + lane + 64];
#pragma unroll
    for (int off = 32; off >= 1; off >>= 1) tt += __shfl_xor(tt, off, 64);
    float val = tt * (1.0f / 12.0f) + cls_b[c];
    if (lane == c) myx = val;
  }
  if (lane < C) x[((size_t)b * C + lane) * HWC + hw] = myx;
}

// ---------------------------------------------------------------------------
// K4: bilinear 4x upsample. Weights via exact integer math; <=3 input rows
// staged in LDS; 2 output rows per block; float4 coalesced stores.
// ---------------------------------------------------------------------------
__global__ __launch_bounds__(256) void k_up(const float* __restrict__ x,
                                            float* __restrict__ out) {
  __shared__ float rows[3 * W];            // 1.5 KB

  const int t = threadIdx.x;
  const size_t base = (size_t)blockIdx.x * 1024;   // first linear output index
  const int bc = (int)(base >> 18);                // output image (b*C+c)
  const int Y0 = ((int)(base >> 9)) & (HO - 1);    // first of 2 output rows

  const int ry = (Y0 * (H - 1)) / (HO - 1);        // lowest needed input row

  if (t < 96) {
    int r  = t >> 5;                               // 0..2
    int xx = (t & 31) * 4;
    int rr = ry + r; if (rr > H - 1) rr = H - 1;
    *(float4*)&rows[r * W + xx] =
        *(const float4*)(x + (size_t)bc * HWC + (size_t)rr * W + xx);
  }
  __syncthreads();

  const int h  = t >> 7;                           // which output row
  const int tt = t & 127;                          // 4 consecutive X each
  const int Y  = Y0 + h;

  const int ynum = Y * (H - 1);
  const int yl   = ynum / (HO - 1);
  const float wy = (float)((double)(ynum - yl * (HO - 1)) * (1.0 / (HO - 1)));
  int yh = yl + 1; if (yh > H - 1) yh = H - 1;
  const float* r0 = &rows[(yl - ry) * W];
  const float* r1 = &rows[(yh - ry) * W];

  float o[4];
#pragma unroll
  for (int j = 0; j < 4; ++j) {
    int X   = 4 * tt + j;
    int num = X * (W - 1);
    int lo  = num / (WO - 1);
    float wx = (float)((double)(num - lo * (WO - 1)) * (1.0 / (WO - 1)));
    int hi = lo + 1; if (hi > W - 1) hi = W - 1;

    float v00 = r0[lo], v01 = r0[hi], v10 = r1[lo], v11 = r1[hi];
    o[j] = (1.f - wy) * ((1.f - wx) * v00 + wx * v01)
         +        wy  * ((1.f - wx) * v10 + wx * v11);
  }
  float4 o4 = {o[0], o[1], o[2], o[3]};
  *(float4*)(out + base + (size_t)h * WO + 4 * tt) = o4;
}

} // namespace

extern "C" void kernel_launch(void* const* d_in, const int* in_sizes, int n_in,
                              void* d_out, int out_size, void* d_ws, size_t ws_size,
                              hipStream_t stream) {
  // inputs: assp, cls_w, cls_b, key_w, key_b, query_w, query_b, px, py
  const float* assp  = (const float*)d_in[0];
  const float* cls_w = (const float*)d_in[1];
  const float* cls_b = (const float*)d_in[2];
  const int*   px    = (const int*)d_in[7];
  const int*   py    = (const int*)d_in[8];
  const int    P     = in_sizes[7];             // 102

  // workspace layout
  char* ws = (char*)d_ws;
  float* sums            = (float*)ws;          // B*C*D = 49152 B
  int*   counts          = (int*)(ws + 49152);  // B*C*4 = 384 B
  float* x               = (float*)(ws + 65536);           // 6 MB
  unsigned char* maskbuf = (unsigned char*)(ws + 8388608); // B*HWC = 256 KB

  float* out = (float*)d_out;

  hipMemsetAsync(ws, 0, 49152 + 384, stream);
  k_cls<<<dim3(HWC / PXC, B), 256, 0, stream>>>(assp, cls_w, cls_b, x, maskbuf, counts);
  k_sum<<<dim3(HWC / 8192, D / 4, B), 256, 0, stream>>>(assp, maskbuf, sums);
  k_patch<<<B * P, 64, 0, stream>>>(assp, sums, counts, cls_w, cls_b, px, py, P, x);
  k_up<<<(B * C * HO * WO) / 1024, 256, 0, stream>>>(x, out);
}

// Round 8
// 264.882 us; speedup vs baseline: 1.2601x; 1.2601x over previous
//
#include <hip/hip_runtime.h>

namespace {

constexpr int B  = 16;
constexpr int D  = 128;
constexpr int C  = 6;
constexpr int H  = 128;
constexpr int W  = 128;
constexpr int HWC = H * W;          // 16384
constexpr int HO = 512, WO = 512;   // 4x upsample
constexpr int TILE = 64;            // pixels per LDS tile
constexpr int TPB  = 2;             // tiles per block (block owns 128 contiguous px)

// ---------------------------------------------------------------------------
// Fused K1+K2: one HBM pass over assp.  (R1-proven structure, 269 us total;
// sole change this round: TPB 4 -> 2 for 2x block-level parallelism.)
// Per 64-px tile staged in LDS (XOR-swizzled, conflict-free both ways):
//   2a: px-ownership dots -> argmax class (register mask) + x = dot/12 + b
//   2b: d-ownership per-class sums, accumulated in registers across tiles
// Register prefetch: tile t+1's global loads are issued right after the
// post-store barrier, so HBM latency hides under 2a/2b compute.
// Block-end: pair-reduce + global atomicAdd into sums[B][C][D], counts[B][C].
// (softmax(...,axis=1).mean(axis=1) == 1/12 -> attention branch is dead code)
// ---------------------------------------------------------------------------
__global__ __launch_bounds__(256) void k_fused(const float* __restrict__ assp,
                                               const float* __restrict__ cls_w,
                                               const float* __restrict__ cls_b,
                                               float* __restrict__ sums,
                                               int* __restrict__ counts,
                                               float* __restrict__ x) {
  __shared__ float tile[D * TILE];      // [d*64 + (px ^ (d&62))], 32 KB
  __shared__ float red[4 * C * TILE];   // red[q][c][px], 6 KB (reused as part[])
  __shared__ float ws[C * D];
  __shared__ float bs[C];

  const int t  = threadIdx.x;
  const int b  = blockIdx.y;
  for (int i = t; i < C * D; i += 256) ws[i] = cls_w[i];
  if (t < C) bs[t] = cls_b[t];

  const int lane = t & 63;
  const int wv   = t >> 6;        // quarter for 2a, wave id
  const int d2b  = t & 127;       // d owned in 2b
  const int h2b  = t >> 7;        // px-half owned in 2b
  const int d1   = t >> 5;        // base d row for staging
  const int px2  = (t & 31) * 2;  // px pair for staging

  float acc2b[C] = {0.f, 0.f, 0.f, 0.f, 0.f, 0.f};
  int   cnt_run  = 0;             // wave0 lane c accumulates count of class c

  const int hw_base = blockIdx.x * (TILE * TPB);
  const float* bbase = assp + ((size_t)b * D) * HWC + hw_base;

  // ---- preload tile 0 into registers (global only, no LDS hazard) ----
  float2 v[16];
#pragma unroll
  for (int j = 0; j < 16; ++j) {
    int d = d1 + 8 * j;
    v[j] = *(const float2*)(bbase + (size_t)d * HWC + px2);
  }

  __syncthreads();                // ws/bs ready

  for (int it = 0; it < TPB; ++it) {
    const int hw0 = hw_base + it * TILE;

    // ---- store prefetched registers -> LDS (swizzled) ----
#pragma unroll
    for (int j = 0; j < 16; ++j) {
      int d = d1 + 8 * j;
      *(float2*)&tile[d * TILE + (px2 ^ (d & 62))] = v[j];
    }
    __syncthreads();

    // ---- issue next tile's global loads; they fly under 2a/2b ----
    if (it + 1 < TPB) {
      const float* nbase = bbase + (it + 1) * TILE;
#pragma unroll
      for (int j = 0; j < 16; ++j) {
        int d = d1 + 8 * j;
        v[j] = *(const float2*)(nbase + (size_t)d * HWC + px2);
      }
    }

    // ---- phase 2a: dots (px = lane, d-quarter = wv) ----
    {
      float a[C] = {0.f, 0.f, 0.f, 0.f, 0.f, 0.f};
#pragma unroll
      for (int dd = 0; dd < 32; ++dd) {
        int d = wv * 32 + dd;
        float vv = tile[d * TILE + (lane ^ (d & 62))];
#pragma unroll
        for (int c = 0; c < C; ++c) a[c] += vv * ws[c * D + d];
      }
#pragma unroll
      for (int c = 0; c < C; ++c) red[(wv * C + c) * TILE + lane] = a[c];
    }
    __syncthreads();

    // ---- finalize (replicated in all waves): class of px = lane ----
    int cls;
    {
      float s[C];
#pragma unroll
      for (int c = 0; c < C; ++c)
        s[c] = red[(0 * C + c) * TILE + lane] + red[(1 * C + c) * TILE + lane]
             + red[(2 * C + c) * TILE + lane] + red[(3 * C + c) * TILE + lane];
      float bv = s[0] + bs[0]; cls = 0;      // first-wins == jnp.argmax
#pragma unroll
      for (int c = 1; c < C; ++c) {
        float pv = s[c] + bs[c];
        if (pv > bv) { bv = pv; cls = c; }
      }
      if (wv == 0) {
        const float inv12 = 1.0f / 12.0f;
        float* xb = x + ((size_t)b * C) * HWC + hw0 + lane;
#pragma unroll
        for (int c = 0; c < C; ++c) xb[(size_t)c * HWC] = s[c] * inv12 + bs[c];
#pragma unroll
        for (int c = 0; c < C; ++c) {
          unsigned long long m = __ballot(cls == c);
          if (lane == c) cnt_run += (int)__popcll(m);
        }
      }
    }

    // ---- phase 2b: per-class sums (d = d2b, px-half = h2b) ----
#pragma unroll
    for (int i = 0; i < 32; ++i) {
      int px = h2b * 32 + i;
      float vv = tile[d2b * TILE + (px ^ (d2b & 62))];
      int c = __shfl(cls, px, 64);           // broadcast: all lanes hold cls(px=lane)
#pragma unroll
      for (int cc = 0; cc < C; ++cc) acc2b[cc] += (c == cc) ? vv : 0.f;
    }
    __syncthreads();                          // before next tile overwrites LDS
  }

  // ---- block epilogue: pair-reduce h halves, one atomic burst per block ----
  float* part = red;                          // reuse (>=768 floats)
  if (h2b == 1) {
#pragma unroll
    for (int c = 0; c < C; ++c) part[c * D + d2b] = acc2b[c];
  }
  __syncthreads();
  if (h2b == 0) {
#pragma unroll
    for (int c = 0; c < C; ++c) {
      float s = acc2b[c] + part[c * D + d2b];
      atomicAdd(&sums[((size_t)b * C + c) * D + d2b], s);
    }
  }
  if (wv == 0 && lane < C) atomicAdd(&counts[b * C + lane], cnt_run);
}

// ---------------------------------------------------------------------------
// K3: per dropped pixel: protoC on the fly from sums/counts, nearest proto
// (first-wins argmin == over the 12=2x6 duplicated list), patch x directly.
// one wave per (b,p); lane owns d and d+64
// ---------------------------------------------------------------------------
__global__ void k_patch(const float* __restrict__ assp,
                        const float* __restrict__ sums,
                        const int* __restrict__ counts,
                        const float* __restrict__ cls_w,
                        const float* __restrict__ cls_b,
                        const int* __restrict__ px,
                        const int* __restrict__ py,
                        int P,
                        float* __restrict__ x) {
  int bp = blockIdx.x;
  int b = bp / P, p = bp % P;
  int hw = px[p] * W + py[p];
  int lane = threadIdx.x;                  // 64 threads = 1 wave
  const float* fbase = assp + ((size_t)b * D) * HWC + hw;

  float f0 = fbase[(size_t)lane * HWC];
  float f1 = fbase[(size_t)(lane + 64) * HWC];

  float pv0[C], pv1[C], ds[C];
#pragma unroll
  for (int c = 0; c < C; ++c) {
    float cnt = (float)counts[b * C + c];
    float s0 = sums[((size_t)b * C + c) * D + lane];
    float s1 = sums[((size_t)b * C + c) * D + lane + 64];
    float q0 = (cnt > 0.f) ? s0 / (cnt + 1e-5f) : 0.f;
    float q1 = (cnt > 0.f) ? s1 / (cnt + 1e-5f) : 0.f;
    pv0[c] = q0; pv1[c] = q1;
    float e0 = q0 - f0, e1 = q1 - f1;
    float tt = e0 * e0 + e1 * e1;
#pragma unroll
    for (int off = 32; off >= 1; off >>= 1) tt += __shfl_xor(tt, off, 64);
    ds[c] = tt;                            // identical on all lanes
  }
  int best = 0; float bv = ds[0];          // first-wins ties == jnp.argmin
#pragma unroll
  for (int c = 1; c < C; ++c)
    if (ds[c] < bv) { bv = ds[c]; best = c; }

  float v0 = 0.f, v1 = 0.f;                // select without dynamic indexing
#pragma unroll
  for (int c = 0; c < C; ++c) {
    if (best == c) { v0 = pv0[c]; v1 = pv1[c]; }
  }

  float myx = 0.f;
#pragma unroll
  for (int c = 0; c < C; ++c) {
    float tt = v0 * cls_w[c * D + lane] + v1 * cls_w[c * D + lane + 64];
#pragma unroll
    for (int off = 32; off >= 1; off >>= 1) tt += __shfl_xor(tt, off, 64);
    float val = tt * (1.0f / 12.0f) + cls_b[c];
    if (lane == c) myx = val;
  }
  if (lane < C) x[((size_t)b * C + lane) * HWC + hw] = myx;
}

// ---------------------------------------------------------------------------
// K4: bilinear 4x upsample. Weights via exact integer math; <=3 input rows
// staged in LDS; 2 output rows per block; float4 coalesced stores.
// ---------------------------------------------------------------------------
__global__ __launch_bounds__(256) void k_up(const float* __restrict__ x,
                                            float* __restrict__ out) {
  __shared__ float rows[3 * W];            // 1.5 KB

  const int t = threadIdx.x;
  const size_t base = (size_t)blockIdx.x * 1024;   // first linear output index
  const int bc = (int)(base >> 18);                // output image (b*C+c)
  const int Y0 = ((int)(base >> 9)) & (HO - 1);    // first of 2 output rows

  const int ry = (Y0 * (H - 1)) / (HO - 1);        // lowest needed input row

  if (t < 96) {
    int r  = t >> 5;                               // 0..2
    int xx = (t & 31) * 4;
    int rr = ry + r; if (rr > H - 1) rr = H - 1;
    *(float4*)&rows[r * W + xx] =
        *(const float4*)(x + (size_t)bc * HWC + (size_t)rr * W + xx);
  }
  __syncthreads();

  const int h  = t >> 7;                           // which output row
  const int tt = t & 127;                          // 4 consecutive X each
  const int Y  = Y0 + h;

  const int ynum = Y * (H - 1);
  const int yl   = ynum / (HO - 1);
  const float wy = (float)((double)(ynum - yl * (HO - 1)) * (1.0 / (HO - 1)));
  int yh = yl + 1; if (yh > H - 1) yh = H - 1;
  const float* r0 = &rows[(yl - ry) * W];
  const float* r1 = &rows[(yh - ry) * W];

  float o[4];
#pragma unroll
  for (int j = 0; j < 4; ++j) {
    int X   = 4 * tt + j;
    int num = X * (W - 1);
    int lo  = num / (WO - 1);
    float wx = (float)((double)(num - lo * (WO - 1)) * (1.0 / (WO - 1)));
    int hi = lo + 1; if (hi > W - 1) hi = W - 1;

    float v00 = r0[lo], v01 = r0[hi], v10 = r1[lo], v11 = r1[hi];
    o[j] = (1.f - wy) * ((1.f - wx) * v00 + wx * v01)
         +        wy  * ((1.f - wx) * v10 + wx * v11);
  }
  float4 o4 = {o[0], o[1], o[2], o[3]};
  *(float4*)(out + base + (size_t)h * WO + 4 * tt) = o4;
}

} // namespace

extern "C" void kernel_launch(void* const* d_in, const int* in_sizes, int n_in,
                              void* d_out, int out_size, void* d_ws, size_t ws_size,
                              hipStream_t stream) {
  // inputs: assp, cls_w, cls_b, key_w, key_b, query_w, query_b, px, py
  const float* assp  = (const float*)d_in[0];
  const float* cls_w = (const float*)d_in[1];
  const float* cls_b = (const float*)d_in[2];
  const int*   px    = (const int*)d_in[7];
  const int*   py    = (const int*)d_in[8];
  const int    P     = in_sizes[7];             // 102

  // workspace layout
  char* ws = (char*)d_ws;
  float* sums   = (float*)ws;                   // B*C*D = 49152 B
  int*   counts = (int*)(ws + 49152);           // B*C*4 = 384 B
  float* x      = (float*)(ws + 65536);         // B*C*HWC = 6 MB

  float* out = (float*)d_out;

  hipMemsetAsync(ws, 0, 49152 + 384, stream);
  k_fused<<<dim3(HWC / (TILE * TPB), B), 256, 0, stream>>>(assp, cls_w, cls_b,
                                                           sums, counts, x);
  k_patch<<<B * P, 64, 0, stream>>>(assp, sums, counts, cls_w, cls_b, px, py, P, x);
  k_up<<<(B * C * HO * WO) / 1024, 256, 0, stream>>>(x, out);
}